// Round 10
// baseline (1133.003 us; speedup 1.0000x reference)
//
#include <hip/hip_runtime.h>
#include <math.h>
#include <float.h>

#define BN_EPS 1e-5f
#define GB 512           // grid blocks; 2/CU on 256 CUs, all co-resident
#define ACAP 8192        // arena ints per 256-node bucket (= 32 KB = v window)
#define PMAX 3328        // max edges per partition chunk (E/GB = 3125)

typedef short s16x8 __attribute__((ext_vector_type(8)));
typedef float f32x4 __attribute__((ext_vector_type(4)));

__device__ __forceinline__ unsigned short f2bf(float f) {
    unsigned u = __float_as_uint(f);
    u += 0x7FFFu + ((u >> 16) & 1u);          // round-to-nearest-even
    return (unsigned short)(u >> 16);
}
__device__ __forceinline__ float bf2f(unsigned short b) {
    return __uint_as_float(((unsigned)b) << 16);
}

union SMem {
    struct {
        int hist[512], lstart[512], goff[512], cur[512];
        int sorted[PMAX];
        unsigned short sbkt[PMAX];
    } p2;                                      // ~28 KB
    float acc[256 * 64];                       // 64 KB (gather tile)
    unsigned short tile[4][16][72];            // mlp LDS round-trip
    struct { float red[4]; float ps[256]; } p5;
};

// Device-scope grid barrier.  R9 post-mortem: polling with atomicAdd(bar,0)
// (an RMW) serialized at the coherence point -> ~200us/barrier.  Fix: arrive
// with ONE agent-scope release fetch_add; poll with agent-scope atomic LOAD
// (plain read, no serialization) at ~0.85us intervals.
__device__ __forceinline__ void gbar(unsigned* bar, unsigned target) {
    __syncthreads();
    if (threadIdx.x == 0) {
        __hip_atomic_fetch_add(bar, 1u, __ATOMIC_RELEASE, __HIP_MEMORY_SCOPE_AGENT);
        int guard = 0;
        while (__hip_atomic_load(bar, __ATOMIC_ACQUIRE, __HIP_MEMORY_SCOPE_AGENT) < target) {
            __builtin_amdgcn_s_sleep(32);     // ~2048 cycles between polls
            if (++guard > (1 << 20)) break;   // bounded spin: fail loud, not hung
        }
        __threadfence();
    }
    __syncthreads();
}

__global__ __launch_bounds__(256, 2) void mega(
    const float* __restrict__ x,
    const int* __restrict__ src, const int* __restrict__ dst,
    const int* __restrict__ batch,
    const float* __restrict__ W1, const float* __restrict__ b1,
    const float* __restrict__ W2, const float* __restrict__ b2,
    const float* __restrict__ Wg, const float* __restrict__ bg,
    const float* __restrict__ bng, const float* __restrict__ bnb,
    const float* __restrict__ bnm, const float* __restrict__ bnv,
    const float* __restrict__ Wl, const float* __restrict__ bl,
    float* __restrict__ out,
    unsigned short* __restrict__ vbuf,      // bf16 v; aliases packed2 arenas
    unsigned short* __restrict__ hxb,       // xb (P1-P3), then h (P4-P5)
    float* __restrict__ gate,
    int* __restrict__ bcur0, unsigned* __restrict__ bar,
    unsigned short* __restrict__ w1t, unsigned short* __restrict__ w2t,
    int N, int E, int G, int NBUCK, int PBLK)
{
    __shared__ SMem sm;
    int tid  = threadIdx.x;
    int lane = tid & 63;
    int wave = tid >> 6;
    int blk  = blockIdx.x;
    int* packed2 = (int*)vbuf;

    // ---------------- P1: prep (xb cvt, weight transpose, zero bcur0) -----
    {
        int n4 = N * 16;
        for (int i = blk * 256 + tid; i < n4; i += GB * 256) {
            float4 f = *(const float4*)(x + (size_t)i * 4);
            ushort4 o;
            o.x = f2bf(f.x); o.y = f2bf(f.y); o.z = f2bf(f.z); o.w = f2bf(f.w);
            *(ushort4*)(hxb + (size_t)i * 4) = o;
        }
        if (blk == 0)
            for (int idx = tid; idx < 4096; idx += 256)
                w1t[idx] = f2bf(W1[(idx & 63) * 64 + (idx >> 6)]);
        if (blk == 1)
            for (int idx = tid; idx < 4096; idx += 256)
                w2t[idx] = f2bf(W2[(idx & 63) * 64 + (idx >> 6)]);
        if (blk == 2) { bcur0[tid] = 0; bcur0[tid + 256] = 0; }
    }
    gbar(bar, 1u * GB);

    // ---------------- P2: partition edges into per-bucket arenas ----------
    {
        int e0  = blk * PBLK;
        int cnt = E - e0; if (cnt > PBLK) cnt = PBLK; if (cnt < 0) cnt = 0;

        sm.p2.hist[tid] = 0; sm.p2.hist[tid + 256] = 0;
        __syncthreads();
        for (int i = tid; i < cnt; i += 256)
            atomicAdd(&sm.p2.hist[dst[e0 + i] >> 8], 1);
        __syncthreads();
        if (tid < 64) {
            int carry = 0;
            for (int c = 0; c < 8; ++c) {
                int v = sm.p2.hist[c * 64 + lane];
                int xv = v;
                #pragma unroll
                for (int d = 1; d < 64; d <<= 1) {
                    int t = __shfl_up(xv, d); if (lane >= d) xv += t;
                }
                sm.p2.lstart[c * 64 + lane] = xv - v + carry;
                carry += __shfl(xv, 63);
            }
        }
        __syncthreads();
        sm.p2.cur[tid] = sm.p2.lstart[tid];
        sm.p2.cur[tid + 256] = sm.p2.lstart[tid + 256];
        for (int b = tid; b < 512; b += 256)
            if (b < NBUCK && sm.p2.hist[b] > 0)
                sm.p2.goff[b] = atomicAdd(&bcur0[b], sm.p2.hist[b]);
        __syncthreads();
        for (int i = tid; i < cnt; i += 256) {
            int d = dst[e0 + i];
            int s = src[e0 + i];
            int b = d >> 8;
            int p = atomicAdd(&sm.p2.cur[b], 1);
            sm.p2.sorted[p] = ((d & 255) << 17) | s;
            sm.p2.sbkt[p] = (unsigned short)b;
        }
        __syncthreads();
        for (int i = tid; i < cnt; i += 256) {
            int b = sm.p2.sbkt[i];
            packed2[(size_t)b * ACAP + sm.p2.goff[b] + (i - sm.p2.lstart[b])]
                = sm.p2.sorted[i];
        }
    }
    gbar(bar, 2u * GB);

    // ---------------- P3: bucket gather (LDS fp32 accumulate) -------------
    if (blk < NBUCK) {
        int b = blk;
        int node0 = b * 256;
        int nn = N - node0; if (nn > 256) nn = 256;

        // init acc = self term (xb rows), coalesced
        for (int idx = tid; idx < 256 * 64; idx += 256) {
            int row = idx >> 6, f = idx & 63;
            sm.acc[idx] = (row < nn)
                ? bf2f(hxb[(size_t)(node0 + row) * 64 + f]) : 0.f;
        }
        __syncthreads();

        int ecnt = bcur0[b];
        const int* arena = packed2 + (size_t)b * ACAP;

        for (int base = wave * 64; base < ecnt; base += 256) {
            int idx2 = base + lane;
            int pk = (idx2 < ecnt) ? arena[idx2] : 0;
            int cnt64 = ecnt - base; if (cnt64 > 64) cnt64 = 64;
            int j = 0;
            for (; j + 16 <= cnt64; j += 16) {
                float t[16]; int dl[16];
                #pragma unroll
                for (int q = 0; q < 16; ++q) {
                    int pv = __builtin_amdgcn_readlane(pk, j + q);
                    dl[q] = pv >> 17;
                    t[q] = bf2f(hxb[(size_t)(pv & 0x1FFFF) * 64 + lane]);
                }
                #pragma unroll
                for (int q = 0; q < 16; ++q)
                    atomicAdd(&sm.acc[dl[q] * 64 + lane], t[q]);
            }
            for (; j < cnt64; ++j) {
                int pv = __builtin_amdgcn_readlane(pk, j);
                atomicAdd(&sm.acc[(pv >> 17) * 64 + lane],
                          bf2f(hxb[(size_t)(pv & 0x1FFFF) * 64 + lane]));
            }
        }
        __syncthreads();   // all arena reads done before overwriting window

        for (int idx = tid; idx < nn * 32; idx += 256) {
            int row = idx >> 5, p = idx & 31;
            unsigned lo = f2bf(sm.acc[row * 64 + 2 * p]);
            unsigned hi = f2bf(sm.acc[row * 64 + 2 * p + 1]);
            ((unsigned*)vbuf)[(size_t)(node0 + row) * 32 + p] = lo | (hi << 16);
        }
    }
    gbar(bar, 3u * GB);

    // ---------------- P4: MFMA MLP over 64-node tiles ---------------------
    {
        int quad = lane >> 4;
        int col  = lane & 15;

        s16x8 w1f[4][2], w2f[4][2];
        #pragma unroll
        for (int nt = 0; nt < 4; ++nt)
            #pragma unroll
            for (int kh = 0; kh < 2; ++kh) {
                int off = (nt * 16 + col) * 64 + kh * 32 + quad * 8;
                w1f[nt][kh] = *(const s16x8*)(w1t + off);
                w2f[nt][kh] = *(const s16x8*)(w2t + off);
            }
        float b1v[4], b2v[4], wgv[4];
        #pragma unroll
        for (int nt = 0; nt < 4; ++nt) {
            b1v[nt] = b1[nt * 16 + col];
            b2v[nt] = b2[nt * 16 + col];
            wgv[nt] = Wg[nt * 16 + col];
        }
        float bgv = bg[0];
        int NT = (N + 63) >> 6;

        for (int t = blk; t < NT; t += GB) {
            int base = t * 64 + wave * 16;
            const unsigned short* vrow = vbuf + (size_t)(base + col) * 64;
            s16x8 a0 = *(const s16x8*)(vrow + quad * 8);
            s16x8 a1 = *(const s16x8*)(vrow + 32 + quad * 8);

            f32x4 acc1[4];
            #pragma unroll
            for (int nt = 0; nt < 4; ++nt) {
                f32x4 c = {0.f, 0.f, 0.f, 0.f};
                c = __builtin_amdgcn_mfma_f32_16x16x32_bf16(a0, w1f[nt][0], c, 0, 0, 0);
                c = __builtin_amdgcn_mfma_f32_16x16x32_bf16(a1, w1f[nt][1], c, 0, 0, 0);
                acc1[nt] = c;
            }
            #pragma unroll
            for (int nt = 0; nt < 4; ++nt)
                #pragma unroll
                for (int r = 0; r < 4; ++r) {
                    float hv = fmaxf(acc1[nt][r] + b1v[nt], 0.f);
                    sm.tile[wave][quad * 4 + r][nt * 16 + col] = f2bf(hv);
                }
            s16x8 g0 = *(const s16x8*)&sm.tile[wave][col][quad * 8];
            s16x8 g1 = *(const s16x8*)&sm.tile[wave][col][32 + quad * 8];

            f32x4 acc2[4];
            #pragma unroll
            for (int nt = 0; nt < 4; ++nt) {
                f32x4 c = {0.f, 0.f, 0.f, 0.f};
                c = __builtin_amdgcn_mfma_f32_16x16x32_bf16(g0, w2f[nt][0], c, 0, 0, 0);
                c = __builtin_amdgcn_mfma_f32_16x16x32_bf16(g1, w2f[nt][1], c, 0, 0, 0);
                acc2[nt] = c;
            }
            float gp[4] = {0.f, 0.f, 0.f, 0.f};
            #pragma unroll
            for (int nt = 0; nt < 4; ++nt)
                #pragma unroll
                for (int r = 0; r < 4; ++r) {
                    float hv = fmaxf(acc2[nt][r] + b2v[nt], 0.f);
                    hxb[(size_t)(base + quad * 4 + r) * 64 + nt * 16 + col] = f2bf(hv);
                    gp[r] = fmaf(hv, wgv[nt], gp[r]);
                }
            #pragma unroll
            for (int r = 0; r < 4; ++r) {
                float tt = gp[r];
                tt += __shfl_xor(tt, 1);
                tt += __shfl_xor(tt, 2);
                tt += __shfl_xor(tt, 4);
                tt += __shfl_xor(tt, 8);
                int node = base + quad * 4 + r;
                if (col == 0 && node < N) gate[node] = tt + bgv;
            }
        }
    }
    gbar(bar, 4u * GB);

    // ---------------- P5: pool + BN + linear + log_softmax ----------------
    for (int g = blk; g < G; g += GB) {
        int lo = 0, hi = N;
        while (lo < hi) { int mid = (lo + hi) >> 1; if (batch[mid] < g) lo = mid + 1; else hi = mid; }
        int start = lo;
        hi = N;
        while (lo < hi) { int mid = (lo + hi) >> 1; if (batch[mid] < g + 1) lo = mid + 1; else hi = mid; }
        int end = lo;

        float m = -FLT_MAX;
        for (int i = start + tid; i < end; i += 256) m = fmaxf(m, gate[i]);
        #pragma unroll
        for (int off = 32; off; off >>= 1) m = fmaxf(m, __shfl_xor(m, off));
        if (lane == 0) sm.p5.red[wave] = m;
        __syncthreads();
        m = fmaxf(fmaxf(sm.p5.red[0], sm.p5.red[1]),
                  fmaxf(sm.p5.red[2], sm.p5.red[3]));
        __syncthreads();

        float s = 0.f;
        for (int i = start + tid; i < end; i += 256) s += expf(gate[i] - m);
        #pragma unroll
        for (int off = 32; off; off >>= 1) s += __shfl_xor(s, off);
        if (lane == 0) sm.p5.red[wave] = s;
        __syncthreads();
        s = sm.p5.red[0] + sm.p5.red[1] + sm.p5.red[2] + sm.p5.red[3];

        float a0 = 0.f, a1 = 0.f, a2 = 0.f, a3 = 0.f;
        int i = start + wave;
        for (; i + 12 < end; i += 16) {
            float e0 = expf(gate[i]      - m);
            float e1 = expf(gate[i + 4]  - m);
            float e2 = expf(gate[i + 8]  - m);
            float e3 = expf(gate[i + 12] - m);
            float t0 = bf2f(hxb[(size_t)(i)      * 64 + lane]);
            float t1 = bf2f(hxb[(size_t)(i + 4)  * 64 + lane]);
            float t2 = bf2f(hxb[(size_t)(i + 8)  * 64 + lane]);
            float t3 = bf2f(hxb[(size_t)(i + 12) * 64 + lane]);
            a0 = fmaf(e0, t0, a0); a1 = fmaf(e1, t1, a1);
            a2 = fmaf(e2, t2, a2); a3 = fmaf(e3, t3, a3);
        }
        for (; i < end; i += 4) {
            float e = expf(gate[i] - m);
            a0 = fmaf(e, bf2f(hxb[(size_t)i * 64 + lane]), a0);
        }
        sm.p5.ps[wave * 64 + lane] = (a0 + a1) + (a2 + a3);
        __syncthreads();

        if (wave == 0) {
            float p = sm.p5.ps[lane] + sm.p5.ps[64 + lane]
                    + sm.p5.ps[128 + lane] + sm.p5.ps[192 + lane];
            p = (end > start) ? (p / s) : 0.f;
            float nrm = (p - bnm[lane]) / sqrtf(bnv[lane] + BN_EPS) * bng[lane] + bnb[lane];
            float l0 = nrm * Wl[lane * 2 + 0];
            float l1 = nrm * Wl[lane * 2 + 1];
            #pragma unroll
            for (int off = 32; off; off >>= 1) {
                l0 += __shfl_xor(l0, off);
                l1 += __shfl_xor(l1, off);
            }
            if (lane == 0) {
                l0 += bl[0];
                l1 += bl[1];
                float mx = fmaxf(l0, l1);
                float lse = mx + logf(expf(l0 - mx) + expf(l1 - mx));
                out[g * 2 + 0] = l0 - lse;
                out[g * 2 + 1] = l1 - lse;
            }
        }
        __syncthreads();
    }
}

// ---------------------------------------------------------------------------
extern "C" void kernel_launch(void* const* d_in, const int* in_sizes, int n_in,
                              void* d_out, int out_size, void* d_ws, size_t ws_size,
                              hipStream_t stream)
{
    const float* x     = (const float*)d_in[0];
    const int*   eidx  = (const int*)d_in[1];   // [2, E]: row0=src, row1=dst
    const int*   batch = (const int*)d_in[2];
    const float* W1    = (const float*)d_in[3];
    const float* b1    = (const float*)d_in[4];
    const float* W2    = (const float*)d_in[5];
    const float* b2    = (const float*)d_in[6];
    const float* Wg    = (const float*)d_in[7];
    const float* bg    = (const float*)d_in[8];
    const float* bng   = (const float*)d_in[9];
    const float* bnb   = (const float*)d_in[10];
    const float* bnm   = (const float*)d_in[11];
    const float* bnv   = (const float*)d_in[12];
    const float* Wl    = (const float*)d_in[13];
    const float* bl    = (const float*)d_in[14];
    float* out = (float*)d_out;

    int N = in_sizes[0] / 64;        // requires N < 131072 (17-bit src pack)
    int E = in_sizes[1] / 2;
    int G = out_size / 2;
    int NP = ((N + 63) / 64) * 64;
    int NBUCK = (N + 255) / 256;     // <= 512
    int PBLK = (E + GB - 1) / GB;    // <= PMAX

    char* w = (char*)d_ws;
    size_t vbytes = (size_t)NBUCK * ACAP * 4;            // >= NP*128
    unsigned short* vbuf = (unsigned short*)w;  w += vbytes;
    unsigned short* hxb  = (unsigned short*)w;  w += (size_t)NP * 64 * 2;
    float* gate  = (float*)w;                   w += ((size_t)N * 4 + 255) / 256 * 256;
    int* bcur0   = (int*)w;                     w += 512 * 4;
    unsigned* bar = (unsigned*)w;               w += 128;
    unsigned short* w1t = (unsigned short*)w;   w += 4096 * 2;
    unsigned short* w2t = (unsigned short*)w;

    const int* src = eidx;
    const int* dst = eidx + E;

    hipMemsetAsync(bar, 0, 128, stream);

    mega<<<GB, 256, 0, stream>>>(x, src, dst, batch, W1, b1, W2, b2, Wg, bg,
                                 bng, bnb, bnm, bnv, Wl, bl, out,
                                 vbuf, hxb, gate, bcur0, bar, w1t, w2t,
                                 N, E, G, NBUCK, PBLK);
}

// Round 11
// 872.541 us; speedup vs baseline: 1.2985x; 1.2985x over previous
//
#include <hip/hip_runtime.h>
#include <math.h>
#include <float.h>

#define BN_EPS 1e-5f
#define PBLK 8192        // edges per partition block
#define ACAP 8192        // arena ints per 256-node bucket (32 KB = v window)

typedef short s16x8 __attribute__((ext_vector_type(8)));
typedef float f32x4 __attribute__((ext_vector_type(4)));

__device__ __forceinline__ unsigned short f2bf(float f) {
    unsigned u = __float_as_uint(f);
    u += 0x7FFFu + ((u >> 16) & 1u);          // round-to-nearest-even
    return (unsigned short)(u >> 16);
}
__device__ __forceinline__ float bf2f(unsigned short b) {
    return __uint_as_float(((unsigned)b) << 16);
}

// ---------------------------------------------------------------------------
// Kernel A: fused prep + partition.
//  - all blocks: stride-convert x fp32 -> xb bf16
//  - block 0/1: transpose W1/W2 -> bf16 n-major
//  - each block: partition its PBLK edge chunk into per-bucket arenas
//    (bucket = dst>>8; LDS counting sort; ONE global atomic per bucket).
//    val = (dst&255)<<17 | src  (requires N < 131072).
// ---------------------------------------------------------------------------
__global__ __launch_bounds__(256) void prep_partition(
    const float* __restrict__ x, unsigned short* __restrict__ xb,
    const float* __restrict__ W1, const float* __restrict__ W2,
    unsigned short* __restrict__ w1t, unsigned short* __restrict__ w2t,
    const int* __restrict__ src, const int* __restrict__ dst,
    int* __restrict__ bcur0, int* __restrict__ packed2,
    int N, int E, int NBUCK)
{
    __shared__ int hist[512], lstart[512], goff[512], cur[512];
    __shared__ int sorted[PBLK];
    __shared__ unsigned short sbkt[PBLK];

    int tid = threadIdx.x;
    int lane = tid & 63;
    int blk = blockIdx.x;

    // --- xb conversion (grid-strided) ---
    int n4 = N * 16;
    for (int i = blk * 256 + tid; i < n4; i += gridDim.x * 256) {
        float4 f = *(const float4*)(x + (size_t)i * 4);
        ushort4 o;
        o.x = f2bf(f.x); o.y = f2bf(f.y); o.z = f2bf(f.z); o.w = f2bf(f.w);
        *(ushort4*)(xb + (size_t)i * 4) = o;
    }
    if (blk == 0)
        for (int idx = tid; idx < 4096; idx += 256)
            w1t[idx] = f2bf(W1[(idx & 63) * 64 + (idx >> 6)]);
    if (blk == 1)
        for (int idx = tid; idx < 4096; idx += 256)
            w2t[idx] = f2bf(W2[(idx & 63) * 64 + (idx >> 6)]);

    // --- edge partition ---
    int e0 = blk * PBLK;
    int cnt = E - e0; if (cnt > PBLK) cnt = PBLK; if (cnt < 0) cnt = 0;

    hist[tid] = 0; hist[tid + 256] = 0;
    __syncthreads();
    for (int i = tid; i < cnt; i += 256)
        atomicAdd(&hist[dst[e0 + i] >> 8], 1);
    __syncthreads();
    if (tid < 64) {
        int carry = 0;
        for (int c = 0; c < 8; ++c) {
            int v = hist[c * 64 + lane];
            int xv = v;
            #pragma unroll
            for (int d = 1; d < 64; d <<= 1) {
                int t = __shfl_up(xv, d); if (lane >= d) xv += t;
            }
            lstart[c * 64 + lane] = xv - v + carry;
            carry += __shfl(xv, 63);
        }
    }
    __syncthreads();
    cur[tid] = lstart[tid];
    cur[tid + 256] = lstart[tid + 256];
    for (int b = tid; b < 512; b += 256)
        if (b < NBUCK && hist[b] > 0)
            goff[b] = atomicAdd(&bcur0[b], hist[b]);
    __syncthreads();
    for (int i = tid; i < cnt; i += 256) {
        int d = dst[e0 + i];
        int s = src[e0 + i];
        int b = d >> 8;
        int p = atomicAdd(&cur[b], 1);
        sorted[p] = ((d & 255) << 17) | s;
        sbkt[p] = (unsigned short)b;
    }
    __syncthreads();
    for (int i = tid; i < cnt; i += 256) {
        int b = sbkt[i];
        packed2[(size_t)b * ACAP + goff[b] + (i - lstart[b])] = sorted[i];
    }
}

// ---------------------------------------------------------------------------
// Kernel B: per-bucket gather via LDS fp32 accumulate.  One block per
// 256-node bucket; acc tile [256][64] fp32 in LDS (64 KB).  Per edge:
// read neighbor row (bf16, coalesced 128B) -> ds_add to local dst row.
// Replaces local_csr + gather_v.  v-write exactly overlays this bucket's
// arena (ACAP ints = 32 KB = v window), so the alias is race-free.
// ---------------------------------------------------------------------------
__global__ __launch_bounds__(256) void csr_gather(
    const unsigned short* __restrict__ xb,
    const int* __restrict__ packed2, const int* __restrict__ bcur0,
    unsigned short* __restrict__ vbuf, int N)
{
    __shared__ float acc[256 * 64];

    int tid = threadIdx.x;
    int lane = tid & 63;
    int wave = tid >> 6;
    int b = blockIdx.x;
    int node0 = b * 256;
    int nn = N - node0; if (nn > 256) nn = 256;

    // init acc = self term (coalesced bf16 rows)
    for (int idx = tid; idx < 256 * 64; idx += 256) {
        int row = idx >> 6, f = idx & 63;
        acc[idx] = (row < nn) ? bf2f(xb[(size_t)(node0 + row) * 64 + f]) : 0.f;
    }
    __syncthreads();

    int ecnt = bcur0[b];
    const int* arena = packed2 + (size_t)b * ACAP;

    for (int base = wave * 64; base < ecnt; base += 256) {
        int idx2 = base + lane;
        int pk = (idx2 < ecnt) ? arena[idx2] : 0;
        int cnt64 = ecnt - base; if (cnt64 > 64) cnt64 = 64;
        int j = 0;
        for (; j + 16 <= cnt64; j += 16) {
            float t[16]; int dl[16];
            #pragma unroll
            for (int q = 0; q < 16; ++q) {
                int pv = __builtin_amdgcn_readlane(pk, j + q);
                dl[q] = pv >> 17;
                t[q] = bf2f(xb[(size_t)(pv & 0x1FFFF) * 64 + lane]);
            }
            #pragma unroll
            for (int q = 0; q < 16; ++q)
                atomicAdd(&acc[dl[q] * 64 + lane], t[q]);
        }
        for (; j < cnt64; ++j) {
            int pv = __builtin_amdgcn_readlane(pk, j);
            atomicAdd(&acc[(pv >> 17) * 64 + lane],
                      bf2f(xb[(size_t)(pv & 0x1FFFF) * 64 + lane]));
        }
    }
    __syncthreads();   // all arena reads done before overwriting the window

    for (int idx = tid; idx < nn * 32; idx += 256) {
        int row = idx >> 5, p = idx & 31;
        unsigned lo = f2bf(acc[row * 64 + 2 * p]);
        unsigned hi = f2bf(acc[row * 64 + 2 * p + 1]);
        ((unsigned*)vbuf)[(size_t)(node0 + row) * 32 + p] = lo | (hi << 16);
    }
}

// ---------------------------------------------------------------------------
// Kernel C: MFMA MLP, 16 nodes/wave (see R5-R8 notes).
// ---------------------------------------------------------------------------
__global__ __launch_bounds__(256) void mlp_mfma(
    const unsigned short* __restrict__ v,
    const unsigned short* __restrict__ w1t, const unsigned short* __restrict__ w2t,
    const float* __restrict__ b1, const float* __restrict__ b2,
    const float* __restrict__ Wg, const float* __restrict__ bg,
    unsigned short* __restrict__ h_out, float* __restrict__ gate_out, int N)
{
    int lane = threadIdx.x & 63;
    int wave = threadIdx.x >> 6;
    int quad = lane >> 4;
    int col  = lane & 15;

    s16x8 w1f[4][2], w2f[4][2];
    #pragma unroll
    for (int nt = 0; nt < 4; ++nt)
        #pragma unroll
        for (int kh = 0; kh < 2; ++kh) {
            int off = (nt * 16 + col) * 64 + kh * 32 + quad * 8;
            w1f[nt][kh] = *(const s16x8*)(w1t + off);
            w2f[nt][kh] = *(const s16x8*)(w2t + off);
        }
    float b1v[4], b2v[4], wgv[4];
    #pragma unroll
    for (int nt = 0; nt < 4; ++nt) {
        b1v[nt] = b1[nt * 16 + col];
        b2v[nt] = b2[nt * 16 + col];
        wgv[nt] = Wg[nt * 16 + col];
    }
    float bgv = bg[0];

    __shared__ unsigned short h1s[4][16][72];   // row pad 64->72: no conflicts
    unsigned short (*tile)[72] = h1s[wave];

    int base = blockIdx.x * 64 + wave * 16;

    const unsigned short* vrow = v + (size_t)(base + col) * 64;
    s16x8 a0 = *(const s16x8*)(vrow + quad * 8);
    s16x8 a1 = *(const s16x8*)(vrow + 32 + quad * 8);

    f32x4 acc[4];
    #pragma unroll
    for (int nt = 0; nt < 4; ++nt) {
        f32x4 c = {0.f, 0.f, 0.f, 0.f};
        c = __builtin_amdgcn_mfma_f32_16x16x32_bf16(a0, w1f[nt][0], c, 0, 0, 0);
        c = __builtin_amdgcn_mfma_f32_16x16x32_bf16(a1, w1f[nt][1], c, 0, 0, 0);
        acc[nt] = c;
    }

    #pragma unroll
    for (int nt = 0; nt < 4; ++nt)
        #pragma unroll
        for (int r = 0; r < 4; ++r) {
            float hv = fmaxf(acc[nt][r] + b1v[nt], 0.f);
            tile[quad * 4 + r][nt * 16 + col] = f2bf(hv);
        }

    s16x8 g0 = *(const s16x8*)&tile[col][quad * 8];
    s16x8 g1 = *(const s16x8*)&tile[col][32 + quad * 8];

    f32x4 acc2[4];
    #pragma unroll
    for (int nt = 0; nt < 4; ++nt) {
        f32x4 c = {0.f, 0.f, 0.f, 0.f};
        c = __builtin_amdgcn_mfma_f32_16x16x32_bf16(g0, w2f[nt][0], c, 0, 0, 0);
        c = __builtin_amdgcn_mfma_f32_16x16x32_bf16(g1, w2f[nt][1], c, 0, 0, 0);
        acc2[nt] = c;
    }

    float gp[4] = {0.f, 0.f, 0.f, 0.f};
    #pragma unroll
    for (int nt = 0; nt < 4; ++nt)
        #pragma unroll
        for (int r = 0; r < 4; ++r) {
            float hv = fmaxf(acc2[nt][r] + b2v[nt], 0.f);
            h_out[(size_t)(base + quad * 4 + r) * 64 + nt * 16 + col] = f2bf(hv);
            gp[r] = fmaf(hv, wgv[nt], gp[r]);
        }
    #pragma unroll
    for (int r = 0; r < 4; ++r) {
        float t = gp[r];
        t += __shfl_xor(t, 1);
        t += __shfl_xor(t, 2);
        t += __shfl_xor(t, 4);
        t += __shfl_xor(t, 8);
        int node = base + quad * 4 + r;
        if (col == 0 && node < N) gate_out[node] = t + bgv;
    }
}

// ---------------------------------------------------------------------------
// Kernel D: per-graph softmax-attention pooling + BN(eval) + linear + lsm.
// ---------------------------------------------------------------------------
__global__ __launch_bounds__(256) void pool_final(
    const unsigned short* __restrict__ h, const float* __restrict__ gate,
    const int* __restrict__ batch,
    const float* __restrict__ gamma_, const float* __restrict__ beta_,
    const float* __restrict__ mean_, const float* __restrict__ var_,
    const float* __restrict__ Wl, const float* __restrict__ bl,
    float* __restrict__ out, int N)
{
    int g = blockIdx.x;
    int tid = threadIdx.x;

    int lo = 0, hi = N;
    while (lo < hi) { int mid = (lo + hi) >> 1; if (batch[mid] < g) lo = mid + 1; else hi = mid; }
    int start = lo;
    hi = N;
    while (lo < hi) { int mid = (lo + hi) >> 1; if (batch[mid] < g + 1) lo = mid + 1; else hi = mid; }
    int end = lo;

    __shared__ float red[4];
    __shared__ float pool_s[4 * 64];

    int lane = tid & 63;
    int wave = tid >> 6;

    float m = -FLT_MAX;
    for (int i = start + tid; i < end; i += 256) m = fmaxf(m, gate[i]);
    #pragma unroll
    for (int off = 32; off; off >>= 1) m = fmaxf(m, __shfl_xor(m, off));
    if (lane == 0) red[wave] = m;
    __syncthreads();
    m = fmaxf(fmaxf(red[0], red[1]), fmaxf(red[2], red[3]));
    __syncthreads();

    float s = 0.f;
    for (int i = start + tid; i < end; i += 256) s += expf(gate[i] - m);
    #pragma unroll
    for (int off = 32; off; off >>= 1) s += __shfl_xor(s, off);
    if (lane == 0) red[wave] = s;
    __syncthreads();
    s = red[0] + red[1] + red[2] + red[3];

    float a0 = 0.f, a1 = 0.f, a2 = 0.f, a3 = 0.f;
    int i = start + wave;
    for (; i + 12 < end; i += 16) {
        float e0 = expf(gate[i]      - m);
        float e1 = expf(gate[i + 4]  - m);
        float e2 = expf(gate[i + 8]  - m);
        float e3 = expf(gate[i + 12] - m);
        float t0 = bf2f(h[(size_t)(i)      * 64 + lane]);
        float t1 = bf2f(h[(size_t)(i + 4)  * 64 + lane]);
        float t2 = bf2f(h[(size_t)(i + 8)  * 64 + lane]);
        float t3 = bf2f(h[(size_t)(i + 12) * 64 + lane]);
        a0 = fmaf(e0, t0, a0);
        a1 = fmaf(e1, t1, a1);
        a2 = fmaf(e2, t2, a2);
        a3 = fmaf(e3, t3, a3);
    }
    for (; i < end; i += 4) {
        float e = expf(gate[i] - m);
        a0 = fmaf(e, bf2f(h[(size_t)i * 64 + lane]), a0);
    }
    pool_s[wave * 64 + lane] = (a0 + a1) + (a2 + a3);
    __syncthreads();

    if (wave == 0) {
        float p = pool_s[lane] + pool_s[64 + lane] + pool_s[128 + lane] + pool_s[192 + lane];
        p = (end > start) ? (p / s) : 0.f;
        float nrm = (p - mean_[lane]) / sqrtf(var_[lane] + BN_EPS) * gamma_[lane] + beta_[lane];
        float l0 = nrm * Wl[lane * 2 + 0];
        float l1 = nrm * Wl[lane * 2 + 1];
        #pragma unroll
        for (int off = 32; off; off >>= 1) {
            l0 += __shfl_xor(l0, off);
            l1 += __shfl_xor(l1, off);
        }
        if (lane == 0) {
            l0 += bl[0];
            l1 += bl[1];
            float mx = fmaxf(l0, l1);
            float lse = mx + logf(expf(l0 - mx) + expf(l1 - mx));
            out[g * 2 + 0] = l0 - lse;
            out[g * 2 + 1] = l1 - lse;
        }
    }
}

// ---------------------------------------------------------------------------
extern "C" void kernel_launch(void* const* d_in, const int* in_sizes, int n_in,
                              void* d_out, int out_size, void* d_ws, size_t ws_size,
                              hipStream_t stream)
{
    const float* x     = (const float*)d_in[0];
    const int*   eidx  = (const int*)d_in[1];   // [2, E]: row0=src, row1=dst
    const int*   batch = (const int*)d_in[2];
    const float* W1    = (const float*)d_in[3];
    const float* b1    = (const float*)d_in[4];
    const float* W2    = (const float*)d_in[5];
    const float* b2    = (const float*)d_in[6];
    const float* Wg    = (const float*)d_in[7];
    const float* bg    = (const float*)d_in[8];
    const float* bng   = (const float*)d_in[9];
    const float* bnb   = (const float*)d_in[10];
    const float* bnm   = (const float*)d_in[11];
    const float* bnv   = (const float*)d_in[12];
    const float* Wl    = (const float*)d_in[13];
    const float* bl    = (const float*)d_in[14];
    float* out = (float*)d_out;

    int N = in_sizes[0] / 64;        // requires N < 131072 (17-bit src pack)
    int E = in_sizes[1] / 2;
    int G = out_size / 2;
    int NP = ((N + 63) / 64) * 64;
    int NBUCK = (N + 255) / 256;     // <= 512
    int EB = (E + PBLK - 1) / PBLK;

    char* w = (char*)d_ws;
    size_t vbytes = (size_t)NBUCK * ACAP * 4;   // arena total (>= NP*128)
    if (vbytes < (size_t)NP * 128) vbytes = (size_t)NP * 128;
    unsigned short* vbuf = (unsigned short*)w;  w += vbytes;
    unsigned short* hxb  = (unsigned short*)w;  w += (size_t)NP * 64 * 2;
    float* gate  = (float*)w;                   w += ((size_t)N * 4 + 255) / 256 * 256;
    int* bcur0   = (int*)w;                     w += 512 * 4;
    unsigned short* w1t = (unsigned short*)w;   w += 4096 * 2;
    unsigned short* w2t = (unsigned short*)w;

    int* packed2 = (int*)vbuf;       // arena aliases v (race-free: 32KB windows)
    const int* src = eidx;
    const int* dst = eidx + E;

    hipMemsetAsync(bcur0, 0, 512 * sizeof(int), stream);

    prep_partition<<<EB, 256, 0, stream>>>(x, hxb, W1, W2, w1t, w2t,
                                           src, dst, bcur0, packed2,
                                           N, E, NBUCK);

    csr_gather    <<<NBUCK, 256, 0, stream>>>(hxb, packed2, bcur0, vbuf, N);

    mlp_mfma      <<<NP / 64, 256, 0, stream>>>(vbuf, w1t, w2t, b1, b2, Wg, bg,
                                                hxb, gate, N);

    pool_final    <<<G, 256, 0, stream>>>(hxb, gate, batch, bng, bnb, bnm, bnv,
                                          Wl, bl, out, N);
}

// Round 12
// 256.293 us; speedup vs baseline: 4.4207x; 3.4045x over previous
//
#include <hip/hip_runtime.h>
#include <math.h>
#include <float.h>

#define BN_EPS 1e-5f
#define PBLK   4096      // edges per partition block
#define NBUCKP 832       // padded bucket count (scan width; N <= 106496)
#define ACAP   4096      // arena ints per 128-node bucket (16 KB = v window)
#define STCAP  3072      // LDS stage capacity (expected bucket max ~2300)

typedef short s16x8 __attribute__((ext_vector_type(8)));
typedef float f32x4 __attribute__((ext_vector_type(4)));

__device__ __forceinline__ unsigned short f2bf(float f) {
    unsigned u = __float_as_uint(f);
    u += 0x7FFFu + ((u >> 16) & 1u);          // round-to-nearest-even
    return (unsigned short)(u >> 16);
}
__device__ __forceinline__ float bf2f(unsigned short b) {
    return __uint_as_float(((unsigned)b) << 16);
}

// ---------------------------------------------------------------------------
// Kernel A: fused prep + partition.
//  - all blocks: stride-convert x fp32 -> xb bf16
//  - block 0/1: transpose W1/W2 -> bf16 n-major
//  - each block: LDS counting-sort its PBLK edge chunk by bucket (dst>>7),
//    reserve arena space with ONE global atomic per touched bucket, write
//    bucket-contiguous runs.  val = (dst&127)<<17 | src  (N < 131072).
// ---------------------------------------------------------------------------
__global__ __launch_bounds__(256) void prep_partition(
    const float* __restrict__ x, unsigned short* __restrict__ xb,
    const float* __restrict__ W1, const float* __restrict__ W2,
    unsigned short* __restrict__ w1t, unsigned short* __restrict__ w2t,
    const int* __restrict__ src, const int* __restrict__ dst,
    int* __restrict__ bcur0, int* __restrict__ packed2,
    int N, int E)
{
    __shared__ int hist[NBUCKP], lstart[NBUCKP], goff[NBUCKP], cur[NBUCKP];
    __shared__ int sorted[PBLK];
    __shared__ unsigned short sbkt[PBLK];

    int tid = threadIdx.x;
    int lane = tid & 63;
    int blk = blockIdx.x;

    // --- xb conversion (grid-strided) ---
    int n4 = N * 16;
    for (int i = blk * 256 + tid; i < n4; i += gridDim.x * 256) {
        float4 f = *(const float4*)(x + (size_t)i * 4);
        ushort4 o;
        o.x = f2bf(f.x); o.y = f2bf(f.y); o.z = f2bf(f.z); o.w = f2bf(f.w);
        *(ushort4*)(xb + (size_t)i * 4) = o;
    }
    if (blk == 0)
        for (int idx = tid; idx < 4096; idx += 256)
            w1t[idx] = f2bf(W1[(idx & 63) * 64 + (idx >> 6)]);
    if (blk == 1)
        for (int idx = tid; idx < 4096; idx += 256)
            w2t[idx] = f2bf(W2[(idx & 63) * 64 + (idx >> 6)]);

    // --- edge partition ---
    int e0 = blk * PBLK;
    int cnt = E - e0; if (cnt > PBLK) cnt = PBLK; if (cnt < 0) cnt = 0;

    for (int i = tid; i < NBUCKP; i += 256) hist[i] = 0;
    __syncthreads();
    for (int i = tid; i < cnt; i += 256)
        atomicAdd(&hist[dst[e0 + i] >> 7], 1);
    __syncthreads();
    if (tid < 64) {
        int carry = 0;
        #pragma unroll
        for (int c = 0; c < NBUCKP / 64; ++c) {
            int idx = c * 64 + lane;
            int v = hist[idx];
            int xv = v;
            #pragma unroll
            for (int d = 1; d < 64; d <<= 1) {
                int t = __shfl_up(xv, d); if (lane >= d) xv += t;
            }
            lstart[idx] = xv - v + carry;
            carry += __shfl(xv, 63);
        }
    }
    __syncthreads();
    for (int i = tid; i < NBUCKP; i += 256) {
        cur[i] = lstart[i];
        if (hist[i] > 0) goff[i] = atomicAdd(&bcur0[i], hist[i]);
    }
    __syncthreads();
    for (int i = tid; i < cnt; i += 256) {
        int d = dst[e0 + i];
        int s = src[e0 + i];
        int b = d >> 7;
        int p = atomicAdd(&cur[b], 1);
        sorted[p] = ((d & 127) << 17) | s;
        sbkt[p] = (unsigned short)b;
    }
    __syncthreads();
    for (int i = tid; i < cnt; i += 256) {
        int b = sbkt[i];
        packed2[(size_t)b * ACAP + goff[b] + (i - lstart[b])] = sorted[i];
    }
}

// ---------------------------------------------------------------------------
// Kernel B: per-bucket sort + gather.  One block per 128-node bucket.
// Phase 1 (cheap, atomics OK): LDS counting-sort ~2050 edges by 7-bit dst.
// Phase 2 (latency-critical, NO atomics): per-node gather with the proven
// 8-accumulator batched-load loop; srcs come from LDS stage.  v-row write
// overlays this bucket's arena exactly (ACAP ints = 16 KB window).
// ---------------------------------------------------------------------------
__global__ __launch_bounds__(256) void bucket_gather(
    const unsigned short* __restrict__ xb,
    const int* __restrict__ packed2, const int* __restrict__ bcur0,
    unsigned short* __restrict__ vbuf, int N)
{
    __shared__ int hist[128], excl[129], cur[128];
    __shared__ int stage[STCAP];

    int tid = threadIdx.x;
    int lane = tid & 63;
    int wave = tid >> 6;
    int b = blockIdx.x;
    int node0 = b * 128;
    int ecnt = bcur0[b];
    const int* arena = packed2 + (size_t)b * ACAP;

    if (tid < 128) hist[tid] = 0;
    __syncthreads();
    for (int i = tid; i < ecnt; i += 256)
        atomicAdd(&hist[arena[i] >> 17], 1);
    __syncthreads();
    if (tid < 64) {
        int carry = 0;
        #pragma unroll
        for (int c = 0; c < 2; ++c) {
            int idx = c * 64 + lane;
            int v = hist[idx];
            int xv = v;
            #pragma unroll
            for (int d = 1; d < 64; d <<= 1) {
                int t = __shfl_up(xv, d); if (lane >= d) xv += t;
            }
            excl[idx] = xv - v + carry;
            carry += __shfl(xv, 63);
        }
        if (lane == 0) excl[128] = carry;
    }
    __syncthreads();
    if (tid < 128) cur[tid] = excl[tid];
    __syncthreads();
    for (int i = tid; i < ecnt; i += 256) {
        int v = arena[i];
        int p = atomicAdd(&cur[v >> 17], 1);
        if (p < STCAP) stage[p] = v & 0x1FFFF;
    }
    __syncthreads();

    // phase 2: per-node gather (wave per node, 8-acc ILP, batched loads)
    for (int ln = wave; ln < 128; ln += 4) {
        int node = node0 + ln;
        if (node >= N) break;
        int beg = excl[ln];
        int end = excl[ln + 1];
        size_t row = (size_t)node * 64;

        float v0 = bf2f(xb[row + lane]);   // self term
        float v1 = 0.f, v2 = 0.f, v3 = 0.f, v4 = 0.f, v5 = 0.f, v6 = 0.f, v7 = 0.f;

        for (int base = beg; base < end; base += 64) {
            int ei = (base + lane < end) ? stage[base + lane] : 0;
            int cnt = end - base; if (cnt > 64) cnt = 64;
            int j = 0;
            for (; j + 8 <= cnt; j += 8) {
                int s0 = __builtin_amdgcn_readlane(ei, j + 0);
                int s1 = __builtin_amdgcn_readlane(ei, j + 1);
                int s2 = __builtin_amdgcn_readlane(ei, j + 2);
                int s3 = __builtin_amdgcn_readlane(ei, j + 3);
                int s4 = __builtin_amdgcn_readlane(ei, j + 4);
                int s5 = __builtin_amdgcn_readlane(ei, j + 5);
                int s6 = __builtin_amdgcn_readlane(ei, j + 6);
                int s7 = __builtin_amdgcn_readlane(ei, j + 7);
                unsigned short t0 = xb[(size_t)s0 * 64 + lane];
                unsigned short t1 = xb[(size_t)s1 * 64 + lane];
                unsigned short t2 = xb[(size_t)s2 * 64 + lane];
                unsigned short t3 = xb[(size_t)s3 * 64 + lane];
                unsigned short t4 = xb[(size_t)s4 * 64 + lane];
                unsigned short t5 = xb[(size_t)s5 * 64 + lane];
                unsigned short t6 = xb[(size_t)s6 * 64 + lane];
                unsigned short t7 = xb[(size_t)s7 * 64 + lane];
                v0 += bf2f(t0); v1 += bf2f(t1); v2 += bf2f(t2); v3 += bf2f(t3);
                v4 += bf2f(t4); v5 += bf2f(t5); v6 += bf2f(t6); v7 += bf2f(t7);
            }
            for (; j < cnt; ++j) {
                int s = __builtin_amdgcn_readlane(ei, j);
                v1 += bf2f(xb[(size_t)s * 64 + lane]);
            }
        }
        float v = ((v0 + v1) + (v2 + v3)) + ((v4 + v5) + (v6 + v7));
        vbuf[row + lane] = f2bf(v);        // overlays this bucket's arena
    }
}

// ---------------------------------------------------------------------------
// Kernel C: MFMA MLP, 16 nodes/wave (see R5-R8 notes).
// ---------------------------------------------------------------------------
__global__ __launch_bounds__(256) void mlp_mfma(
    const unsigned short* __restrict__ v,
    const unsigned short* __restrict__ w1t, const unsigned short* __restrict__ w2t,
    const float* __restrict__ b1, const float* __restrict__ b2,
    const float* __restrict__ Wg, const float* __restrict__ bg,
    unsigned short* __restrict__ h_out, float* __restrict__ gate_out, int N)
{
    int lane = threadIdx.x & 63;
    int wave = threadIdx.x >> 6;
    int quad = lane >> 4;
    int col  = lane & 15;

    s16x8 w1f[4][2], w2f[4][2];
    #pragma unroll
    for (int nt = 0; nt < 4; ++nt)
        #pragma unroll
        for (int kh = 0; kh < 2; ++kh) {
            int off = (nt * 16 + col) * 64 + kh * 32 + quad * 8;
            w1f[nt][kh] = *(const s16x8*)(w1t + off);
            w2f[nt][kh] = *(const s16x8*)(w2t + off);
        }
    float b1v[4], b2v[4], wgv[4];
    #pragma unroll
    for (int nt = 0; nt < 4; ++nt) {
        b1v[nt] = b1[nt * 16 + col];
        b2v[nt] = b2[nt * 16 + col];
        wgv[nt] = Wg[nt * 16 + col];
    }
    float bgv = bg[0];

    __shared__ unsigned short h1s[4][16][72];   // row pad 64->72: no conflicts
    unsigned short (*tile)[72] = h1s[wave];

    int base = blockIdx.x * 64 + wave * 16;

    const unsigned short* vrow = v + (size_t)(base + col) * 64;
    s16x8 a0 = *(const s16x8*)(vrow + quad * 8);
    s16x8 a1 = *(const s16x8*)(vrow + 32 + quad * 8);

    f32x4 acc[4];
    #pragma unroll
    for (int nt = 0; nt < 4; ++nt) {
        f32x4 c = {0.f, 0.f, 0.f, 0.f};
        c = __builtin_amdgcn_mfma_f32_16x16x32_bf16(a0, w1f[nt][0], c, 0, 0, 0);
        c = __builtin_amdgcn_mfma_f32_16x16x32_bf16(a1, w1f[nt][1], c, 0, 0, 0);
        acc[nt] = c;
    }

    #pragma unroll
    for (int nt = 0; nt < 4; ++nt)
        #pragma unroll
        for (int r = 0; r < 4; ++r) {
            float hv = fmaxf(acc[nt][r] + b1v[nt], 0.f);
            tile[quad * 4 + r][nt * 16 + col] = f2bf(hv);
        }

    s16x8 g0 = *(const s16x8*)&tile[col][quad * 8];
    s16x8 g1 = *(const s16x8*)&tile[col][32 + quad * 8];

    f32x4 acc2[4];
    #pragma unroll
    for (int nt = 0; nt < 4; ++nt) {
        f32x4 c = {0.f, 0.f, 0.f, 0.f};
        c = __builtin_amdgcn_mfma_f32_16x16x32_bf16(g0, w2f[nt][0], c, 0, 0, 0);
        c = __builtin_amdgcn_mfma_f32_16x16x32_bf16(g1, w2f[nt][1], c, 0, 0, 0);
        acc2[nt] = c;
    }

    float gp[4] = {0.f, 0.f, 0.f, 0.f};
    #pragma unroll
    for (int nt = 0; nt < 4; ++nt)
        #pragma unroll
        for (int r = 0; r < 4; ++r) {
            float hv = fmaxf(acc2[nt][r] + b2v[nt], 0.f);
            h_out[(size_t)(base + quad * 4 + r) * 64 + nt * 16 + col] = f2bf(hv);
            gp[r] = fmaf(hv, wgv[nt], gp[r]);
        }
    #pragma unroll
    for (int r = 0; r < 4; ++r) {
        float t = gp[r];
        t += __shfl_xor(t, 1);
        t += __shfl_xor(t, 2);
        t += __shfl_xor(t, 4);
        t += __shfl_xor(t, 8);
        int node = base + quad * 4 + r;
        if (col == 0 && node < N) gate_out[node] = t + bgv;
    }
}

// ---------------------------------------------------------------------------
// Kernel D: per-graph softmax-attention pooling + BN(eval) + linear + lsm.
// ---------------------------------------------------------------------------
__global__ __launch_bounds__(256) void pool_final(
    const unsigned short* __restrict__ h, const float* __restrict__ gate,
    const int* __restrict__ batch,
    const float* __restrict__ gamma_, const float* __restrict__ beta_,
    const float* __restrict__ mean_, const float* __restrict__ var_,
    const float* __restrict__ Wl, const float* __restrict__ bl,
    float* __restrict__ out, int N)
{
    int g = blockIdx.x;
    int tid = threadIdx.x;

    int lo = 0, hi = N;
    while (lo < hi) { int mid = (lo + hi) >> 1; if (batch[mid] < g) lo = mid + 1; else hi = mid; }
    int start = lo;
    hi = N;
    while (lo < hi) { int mid = (lo + hi) >> 1; if (batch[mid] < g + 1) lo = mid + 1; else hi = mid; }
    int end = lo;

    __shared__ float red[4];
    __shared__ float pool_s[4 * 64];

    int lane = tid & 63;
    int wave = tid >> 6;

    float m = -FLT_MAX;
    for (int i = start + tid; i < end; i += 256) m = fmaxf(m, gate[i]);
    #pragma unroll
    for (int off = 32; off; off >>= 1) m = fmaxf(m, __shfl_xor(m, off));
    if (lane == 0) red[wave] = m;
    __syncthreads();
    m = fmaxf(fmaxf(red[0], red[1]), fmaxf(red[2], red[3]));
    __syncthreads();

    float s = 0.f;
    for (int i = start + tid; i < end; i += 256) s += expf(gate[i] - m);
    #pragma unroll
    for (int off = 32; off; off >>= 1) s += __shfl_xor(s, off);
    if (lane == 0) red[wave] = s;
    __syncthreads();
    s = red[0] + red[1] + red[2] + red[3];

    float a0 = 0.f, a1 = 0.f, a2 = 0.f, a3 = 0.f;
    int i = start + wave;
    for (; i + 12 < end; i += 16) {
        float e0 = expf(gate[i]      - m);
        float e1 = expf(gate[i + 4]  - m);
        float e2 = expf(gate[i + 8]  - m);
        float e3 = expf(gate[i + 12] - m);
        float t0 = bf2f(h[(size_t)(i)      * 64 + lane]);
        float t1 = bf2f(h[(size_t)(i + 4)  * 64 + lane]);
        float t2 = bf2f(h[(size_t)(i + 8)  * 64 + lane]);
        float t3 = bf2f(h[(size_t)(i + 12) * 64 + lane]);
        a0 = fmaf(e0, t0, a0);
        a1 = fmaf(e1, t1, a1);
        a2 = fmaf(e2, t2, a2);
        a3 = fmaf(e3, t3, a3);
    }
    for (; i < end; i += 4) {
        float e = expf(gate[i] - m);
        a0 = fmaf(e, bf2f(h[(size_t)i * 64 + lane]), a0);
    }
    pool_s[wave * 64 + lane] = (a0 + a1) + (a2 + a3);
    __syncthreads();

    if (wave == 0) {
        float p = pool_s[lane] + pool_s[64 + lane] + pool_s[128 + lane] + pool_s[192 + lane];
        p = (end > start) ? (p / s) : 0.f;
        float nrm = (p - mean_[lane]) / sqrtf(var_[lane] + BN_EPS) * gamma_[lane] + beta_[lane];
        float l0 = nrm * Wl[lane * 2 + 0];
        float l1 = nrm * Wl[lane * 2 + 1];
        #pragma unroll
        for (int off = 32; off; off >>= 1) {
            l0 += __shfl_xor(l0, off);
            l1 += __shfl_xor(l1, off);
        }
        if (lane == 0) {
            l0 += bl[0];
            l1 += bl[1];
            float mx = fmaxf(l0, l1);
            float lse = mx + logf(expf(l0 - mx) + expf(l1 - mx));
            out[g * 2 + 0] = l0 - lse;
            out[g * 2 + 1] = l1 - lse;
        }
    }
}

// ---------------------------------------------------------------------------
extern "C" void kernel_launch(void* const* d_in, const int* in_sizes, int n_in,
                              void* d_out, int out_size, void* d_ws, size_t ws_size,
                              hipStream_t stream)
{
    const float* x     = (const float*)d_in[0];
    const int*   eidx  = (const int*)d_in[1];   // [2, E]: row0=src, row1=dst
    const int*   batch = (const int*)d_in[2];
    const float* W1    = (const float*)d_in[3];
    const float* b1    = (const float*)d_in[4];
    const float* W2    = (const float*)d_in[5];
    const float* b2    = (const float*)d_in[6];
    const float* Wg    = (const float*)d_in[7];
    const float* bg    = (const float*)d_in[8];
    const float* bng   = (const float*)d_in[9];
    const float* bnb   = (const float*)d_in[10];
    const float* bnm   = (const float*)d_in[11];
    const float* bnv   = (const float*)d_in[12];
    const float* Wl    = (const float*)d_in[13];
    const float* bl    = (const float*)d_in[14];
    float* out = (float*)d_out;

    int N = in_sizes[0] / 64;        // requires N < 131072 (17-bit src pack)
    int E = in_sizes[1] / 2;
    int G = out_size / 2;
    int NP = ((N + 63) / 64) * 64;
    int NBUCK = (N + 127) / 128;     // <= NBUCKP
    int EB = (E + PBLK - 1) / PBLK;

    char* w = (char*)d_ws;
    size_t vbytes = (size_t)NBUCK * ACAP * 4;   // = NBUCK*128 rows * 128B >= NP*128
    unsigned short* vbuf = (unsigned short*)w;  w += vbytes;
    unsigned short* hxb  = (unsigned short*)w;  w += (size_t)NP * 64 * 2;
    float* gate  = (float*)w;                   w += ((size_t)N * 4 + 255) / 256 * 256;
    int* bcur0   = (int*)w;                     w += NBUCKP * 4;
    unsigned short* w1t = (unsigned short*)w;   w += 4096 * 2;
    unsigned short* w2t = (unsigned short*)w;

    int* packed2 = (int*)vbuf;       // arenas alias v (16 KB windows, race-free)
    const int* src = eidx;
    const int* dst = eidx + E;

    hipMemsetAsync(bcur0, 0, NBUCKP * sizeof(int), stream);

    prep_partition<<<EB, 256, 0, stream>>>(x, hxb, W1, W2, w1t, w2t,
                                           src, dst, bcur0, packed2, N, E);

    bucket_gather <<<NBUCK, 256, 0, stream>>>(hxb, packed2, bcur0, vbuf, N);

    mlp_mfma      <<<NP / 64, 256, 0, stream>>>(vbuf, w1t, w2t, b1, b2, Wg, bg,
                                                hxb, gate, N);

    pool_final    <<<G, 256, 0, stream>>>(hxb, gate, batch, bng, bnb, bnm, bnv,
                                          Wl, bl, out, N);
}

// Round 13
// 215.095 us; speedup vs baseline: 5.2675x; 1.1915x over previous
//
#include <hip/hip_runtime.h>
#include <math.h>
#include <float.h>

#define BN_EPS 1e-5f
#define PBLK   8192      // edges per partition block
#define NBUCKP 832       // padded bucket count (scan width; N <= 106496)
#define ACAP   4096      // arena ints per 128-node bucket
#define STCAP  3072      // LDS stage capacity (expected bucket max ~2350)

typedef short s16x8 __attribute__((ext_vector_type(8)));
typedef float f32x4 __attribute__((ext_vector_type(4)));

__device__ __forceinline__ unsigned short f2bf(float f) {
    unsigned u = __float_as_uint(f);
    u += 0x7FFFu + ((u >> 16) & 1u);          // round-to-nearest-even
    return (unsigned short)(u >> 16);
}
__device__ __forceinline__ float bf2f(unsigned short b) {
    return __uint_as_float(((unsigned)b) << 16);
}

// ---------------------------------------------------------------------------
// Kernel A: fused prep + partition (PBLK=8192 -> ~10-edge contiguous runs).
//  - all blocks: stride-convert x fp32 -> xb bf16
//  - block 0/1: transpose W1/W2 -> bf16 n-major
//  - each block: LDS counting-sort its edge chunk by bucket (dst>>7), one
//    global atomic per touched bucket, bucket-contiguous writeout.
//    val = (dst&127)<<17 | src  (requires N < 131072).
// ---------------------------------------------------------------------------
__global__ __launch_bounds__(256) void prep_partition(
    const float* __restrict__ x, unsigned short* __restrict__ xb,
    const float* __restrict__ W1, const float* __restrict__ W2,
    unsigned short* __restrict__ w1t, unsigned short* __restrict__ w2t,
    const int* __restrict__ src, const int* __restrict__ dst,
    int* __restrict__ bcur0, int* __restrict__ packed2,
    int N, int E)
{
    __shared__ int hist[NBUCKP], lstart[NBUCKP], goff[NBUCKP], cur[NBUCKP];
    __shared__ int sorted[PBLK];
    __shared__ unsigned short sbkt[PBLK];

    int tid = threadIdx.x;
    int lane = tid & 63;
    int blk = blockIdx.x;

    // --- xb conversion (grid-strided) ---
    int n4 = N * 16;
    for (int i = blk * 256 + tid; i < n4; i += gridDim.x * 256) {
        float4 f = *(const float4*)(x + (size_t)i * 4);
        ushort4 o;
        o.x = f2bf(f.x); o.y = f2bf(f.y); o.z = f2bf(f.z); o.w = f2bf(f.w);
        *(ushort4*)(xb + (size_t)i * 4) = o;
    }
    if (blk == 0)
        for (int idx = tid; idx < 4096; idx += 256)
            w1t[idx] = f2bf(W1[(idx & 63) * 64 + (idx >> 6)]);
    if (blk == 1)
        for (int idx = tid; idx < 4096; idx += 256)
            w2t[idx] = f2bf(W2[(idx & 63) * 64 + (idx >> 6)]);

    // --- edge partition ---
    int e0 = blk * PBLK;
    int cnt = E - e0; if (cnt > PBLK) cnt = PBLK; if (cnt < 0) cnt = 0;

    for (int i = tid; i < NBUCKP; i += 256) hist[i] = 0;
    __syncthreads();
    for (int i = tid; i < cnt; i += 256)
        atomicAdd(&hist[dst[e0 + i] >> 7], 1);
    __syncthreads();
    if (tid < 64) {
        int carry = 0;
        #pragma unroll
        for (int c = 0; c < NBUCKP / 64; ++c) {
            int idx = c * 64 + lane;
            int v = hist[idx];
            int xv = v;
            #pragma unroll
            for (int d = 1; d < 64; d <<= 1) {
                int t = __shfl_up(xv, d); if (lane >= d) xv += t;
            }
            lstart[idx] = xv - v + carry;
            carry += __shfl(xv, 63);
        }
    }
    __syncthreads();
    for (int i = tid; i < NBUCKP; i += 256) {
        cur[i] = lstart[i];
        if (hist[i] > 0) goff[i] = atomicAdd(&bcur0[i], hist[i]);
    }
    __syncthreads();
    for (int i = tid; i < cnt; i += 256) {
        int d = dst[e0 + i];
        int s = src[e0 + i];
        int b = d >> 7;
        int p = atomicAdd(&cur[b], 1);
        sorted[p] = ((d & 127) << 17) | s;
        sbkt[p] = (unsigned short)b;
    }
    __syncthreads();
    for (int i = tid; i < cnt; i += 256) {
        int b = sbkt[i];
        packed2[(size_t)b * ACAP + goff[b] + (i - lstart[b])] = sorted[i];
    }
}

// ---------------------------------------------------------------------------
// Kernel B: fused per-bucket sort + gather + MFMA MLP.  512 thr = 8 waves,
// one block per 128-node bucket.
//  phase 1 (atomics OK): LDS counting-sort ~2050 edges by 7-bit dst.
//  phase 2 (NO atomics): wave w gathers its own 16 consecutive nodes with
//    the 8-accumulator batched-load loop, writes rows to LDS v-tile.
//  phase 3: wave w runs the 16-node MFMA MLP on its OWN tile rows (same-wave
//    LDS -> in-order, no barrier), emits h (bf16) + gate to global.
// ---------------------------------------------------------------------------
__global__ __launch_bounds__(512) void bucket_fused(
    const unsigned short* __restrict__ xb,
    const int* __restrict__ packed2, const int* __restrict__ bcur0,
    const unsigned short* __restrict__ w1t, const unsigned short* __restrict__ w2t,
    const float* __restrict__ b1, const float* __restrict__ b2,
    const float* __restrict__ Wg, const float* __restrict__ bg,
    unsigned short* __restrict__ h_out, float* __restrict__ gate_out, int N)
{
    __shared__ int hist[128], excl[129], cur[128];
    __shared__ int stage[STCAP];
    __shared__ unsigned short vt[128][72];     // pad 64->72: conflict-free b128

    int tid = threadIdx.x;
    int lane = tid & 63;
    int wave = tid >> 6;                       // 0..7
    int b = blockIdx.x;
    int node0 = b * 128;
    int ecnt = bcur0[b];
    const int* arena = packed2 + (size_t)b * ACAP;

    // ---- phase 1: counting sort by local dst ----
    if (tid < 128) hist[tid] = 0;
    __syncthreads();
    for (int i = tid; i < ecnt; i += 512)
        atomicAdd(&hist[arena[i] >> 17], 1);
    __syncthreads();
    if (tid < 64) {
        int carry = 0;
        #pragma unroll
        for (int c = 0; c < 2; ++c) {
            int idx = c * 64 + lane;
            int v = hist[idx];
            int xv = v;
            #pragma unroll
            for (int d = 1; d < 64; d <<= 1) {
                int t = __shfl_up(xv, d); if (lane >= d) xv += t;
            }
            excl[idx] = xv - v + carry;
            carry += __shfl(xv, 63);
        }
        if (lane == 0) excl[128] = carry;
    }
    __syncthreads();
    if (tid < 128) cur[tid] = excl[tid];
    __syncthreads();
    for (int i = tid; i < ecnt; i += 512) {
        int v = arena[i];
        int p = atomicAdd(&cur[v >> 17], 1);
        if (p < STCAP) stage[p] = v & 0x1FFFF;
    }
    __syncthreads();

    // ---- phase 2: gather 16 consecutive nodes per wave ----
    int rowbase = wave * 16;
    for (int m = 0; m < 16; ++m) {
        int ln = rowbase + m;
        int node = node0 + ln;
        if (node < N) {
            int beg = excl[ln];     if (beg > STCAP) beg = STCAP;
            int end = excl[ln + 1]; if (end > STCAP) end = STCAP;

            float v0 = bf2f(xb[(size_t)node * 64 + lane]);   // self term
            float v1 = 0.f, v2 = 0.f, v3 = 0.f, v4 = 0.f, v5 = 0.f, v6 = 0.f, v7 = 0.f;

            for (int base = beg; base < end; base += 64) {
                int ei = (base + lane < end) ? stage[base + lane] : 0;
                int cnt = end - base; if (cnt > 64) cnt = 64;
                int j = 0;
                for (; j + 8 <= cnt; j += 8) {
                    int s0 = __builtin_amdgcn_readlane(ei, j + 0);
                    int s1 = __builtin_amdgcn_readlane(ei, j + 1);
                    int s2 = __builtin_amdgcn_readlane(ei, j + 2);
                    int s3 = __builtin_amdgcn_readlane(ei, j + 3);
                    int s4 = __builtin_amdgcn_readlane(ei, j + 4);
                    int s5 = __builtin_amdgcn_readlane(ei, j + 5);
                    int s6 = __builtin_amdgcn_readlane(ei, j + 6);
                    int s7 = __builtin_amdgcn_readlane(ei, j + 7);
                    unsigned short t0 = xb[(size_t)s0 * 64 + lane];
                    unsigned short t1 = xb[(size_t)s1 * 64 + lane];
                    unsigned short t2 = xb[(size_t)s2 * 64 + lane];
                    unsigned short t3 = xb[(size_t)s3 * 64 + lane];
                    unsigned short t4 = xb[(size_t)s4 * 64 + lane];
                    unsigned short t5 = xb[(size_t)s5 * 64 + lane];
                    unsigned short t6 = xb[(size_t)s6 * 64 + lane];
                    unsigned short t7 = xb[(size_t)s7 * 64 + lane];
                    v0 += bf2f(t0); v1 += bf2f(t1); v2 += bf2f(t2); v3 += bf2f(t3);
                    v4 += bf2f(t4); v5 += bf2f(t5); v6 += bf2f(t6); v7 += bf2f(t7);
                }
                for (; j < cnt; ++j) {
                    int s = __builtin_amdgcn_readlane(ei, j);
                    v1 += bf2f(xb[(size_t)s * 64 + lane]);
                }
            }
            float v = ((v0 + v1) + (v2 + v3)) + ((v4 + v5) + (v6 + v7));
            vt[ln][lane] = f2bf(v);
        } else {
            vt[ln][lane] = 0;
        }
    }
    // no barrier: phase 3 reads only this wave's own rows (same-wave DS order)

    // ---- phase 3: 16-node MFMA MLP on own tile ----
    {
        int quad = lane >> 4;
        int col  = lane & 15;

        s16x8 a0 = *(const s16x8*)&vt[rowbase + col][quad * 8];
        s16x8 a1 = *(const s16x8*)&vt[rowbase + col][32 + quad * 8];

        float b1v[4], b2v[4], wgv[4];
        #pragma unroll
        for (int nt = 0; nt < 4; ++nt) {
            b1v[nt] = b1[nt * 16 + col];
            b2v[nt] = b2[nt * 16 + col];
            wgv[nt] = Wg[nt * 16 + col];
        }
        float bgv = bg[0];

        f32x4 acc1[4];
        #pragma unroll
        for (int nt = 0; nt < 4; ++nt) {
            int off = (nt * 16 + col) * 64 + quad * 8;
            s16x8 w0 = *(const s16x8*)(w1t + off);
            s16x8 w1 = *(const s16x8*)(w1t + off + 32);
            f32x4 c = {0.f, 0.f, 0.f, 0.f};
            c = __builtin_amdgcn_mfma_f32_16x16x32_bf16(a0, w0, c, 0, 0, 0);
            c = __builtin_amdgcn_mfma_f32_16x16x32_bf16(a1, w1, c, 0, 0, 0);
            acc1[nt] = c;
        }
        #pragma unroll
        for (int nt = 0; nt < 4; ++nt)
            #pragma unroll
            for (int r = 0; r < 4; ++r) {
                float hv = fmaxf(acc1[nt][r] + b1v[nt], 0.f);
                vt[rowbase + quad * 4 + r][nt * 16 + col] = f2bf(hv);
            }

        s16x8 g0 = *(const s16x8*)&vt[rowbase + col][quad * 8];
        s16x8 g1 = *(const s16x8*)&vt[rowbase + col][32 + quad * 8];

        f32x4 acc2[4];
        #pragma unroll
        for (int nt = 0; nt < 4; ++nt) {
            int off = (nt * 16 + col) * 64 + quad * 8;
            s16x8 w0 = *(const s16x8*)(w2t + off);
            s16x8 w1 = *(const s16x8*)(w2t + off + 32);
            f32x4 c = {0.f, 0.f, 0.f, 0.f};
            c = __builtin_amdgcn_mfma_f32_16x16x32_bf16(g0, w0, c, 0, 0, 0);
            c = __builtin_amdgcn_mfma_f32_16x16x32_bf16(g1, w1, c, 0, 0, 0);
            acc2[nt] = c;
        }

        int nbase = node0 + rowbase;
        float gp[4] = {0.f, 0.f, 0.f, 0.f};
        #pragma unroll
        for (int nt = 0; nt < 4; ++nt)
            #pragma unroll
            for (int r = 0; r < 4; ++r) {
                float hv = fmaxf(acc2[nt][r] + b2v[nt], 0.f);
                int node = nbase + quad * 4 + r;
                if (node < N)
                    h_out[(size_t)node * 64 + nt * 16 + col] = f2bf(hv);
                gp[r] = fmaf(hv, wgv[nt], gp[r]);
            }
        #pragma unroll
        for (int r = 0; r < 4; ++r) {
            float t = gp[r];
            t += __shfl_xor(t, 1);
            t += __shfl_xor(t, 2);
            t += __shfl_xor(t, 4);
            t += __shfl_xor(t, 8);
            int node = nbase + quad * 4 + r;
            if (col == 0 && node < N) gate_out[node] = t + bgv;
        }
    }
}

// ---------------------------------------------------------------------------
// Kernel C: per-graph softmax-attention pooling + BN(eval) + linear + lsm.
// ---------------------------------------------------------------------------
__global__ __launch_bounds__(256) void pool_final(
    const unsigned short* __restrict__ h, const float* __restrict__ gate,
    const int* __restrict__ batch,
    const float* __restrict__ gamma_, const float* __restrict__ beta_,
    const float* __restrict__ mean_, const float* __restrict__ var_,
    const float* __restrict__ Wl, const float* __restrict__ bl,
    float* __restrict__ out, int N)
{
    int g = blockIdx.x;
    int tid = threadIdx.x;

    int lo = 0, hi = N;
    while (lo < hi) { int mid = (lo + hi) >> 1; if (batch[mid] < g) lo = mid + 1; else hi = mid; }
    int start = lo;
    hi = N;
    while (lo < hi) { int mid = (lo + hi) >> 1; if (batch[mid] < g + 1) lo = mid + 1; else hi = mid; }
    int end = lo;

    __shared__ float red[4];
    __shared__ float pool_s[4 * 64];

    int lane = tid & 63;
    int wave = tid >> 6;

    float m = -FLT_MAX;
    for (int i = start + tid; i < end; i += 256) m = fmaxf(m, gate[i]);
    #pragma unroll
    for (int off = 32; off; off >>= 1) m = fmaxf(m, __shfl_xor(m, off));
    if (lane == 0) red[wave] = m;
    __syncthreads();
    m = fmaxf(fmaxf(red[0], red[1]), fmaxf(red[2], red[3]));
    __syncthreads();

    float s = 0.f;
    for (int i = start + tid; i < end; i += 256) s += expf(gate[i] - m);
    #pragma unroll
    for (int off = 32; off; off >>= 1) s += __shfl_xor(s, off);
    if (lane == 0) red[wave] = s;
    __syncthreads();
    s = red[0] + red[1] + red[2] + red[3];

    float a0 = 0.f, a1 = 0.f, a2 = 0.f, a3 = 0.f;
    int i = start + wave;
    for (; i + 12 < end; i += 16) {
        float e0 = expf(gate[i]      - m);
        float e1 = expf(gate[i + 4]  - m);
        float e2 = expf(gate[i + 8]  - m);
        float e3 = expf(gate[i + 12] - m);
        float t0 = bf2f(h[(size_t)(i)      * 64 + lane]);
        float t1 = bf2f(h[(size_t)(i + 4)  * 64 + lane]);
        float t2 = bf2f(h[(size_t)(i + 8)  * 64 + lane]);
        float t3 = bf2f(h[(size_t)(i + 12) * 64 + lane]);
        a0 = fmaf(e0, t0, a0);
        a1 = fmaf(e1, t1, a1);
        a2 = fmaf(e2, t2, a2);
        a3 = fmaf(e3, t3, a3);
    }
    for (; i < end; i += 4) {
        float e = expf(gate[i] - m);
        a0 = fmaf(e, bf2f(h[(size_t)i * 64 + lane]), a0);
    }
    pool_s[wave * 64 + lane] = (a0 + a1) + (a2 + a3);
    __syncthreads();

    if (wave == 0) {
        float p = pool_s[lane] + pool_s[64 + lane] + pool_s[128 + lane] + pool_s[192 + lane];
        p = (end > start) ? (p / s) : 0.f;
        float nrm = (p - mean_[lane]) / sqrtf(var_[lane] + BN_EPS) * gamma_[lane] + beta_[lane];
        float l0 = nrm * Wl[lane * 2 + 0];
        float l1 = nrm * Wl[lane * 2 + 1];
        #pragma unroll
        for (int off = 32; off; off >>= 1) {
            l0 += __shfl_xor(l0, off);
            l1 += __shfl_xor(l1, off);
        }
        if (lane == 0) {
            l0 += bl[0];
            l1 += bl[1];
            float mx = fmaxf(l0, l1);
            float lse = mx + logf(expf(l0 - mx) + expf(l1 - mx));
            out[g * 2 + 0] = l0 - lse;
            out[g * 2 + 1] = l1 - lse;
        }
    }
}

// ---------------------------------------------------------------------------
extern "C" void kernel_launch(void* const* d_in, const int* in_sizes, int n_in,
                              void* d_out, int out_size, void* d_ws, size_t ws_size,
                              hipStream_t stream)
{
    const float* x     = (const float*)d_in[0];
    const int*   eidx  = (const int*)d_in[1];   // [2, E]: row0=src, row1=dst
    const int*   batch = (const int*)d_in[2];
    const float* W1    = (const float*)d_in[3];
    const float* b1    = (const float*)d_in[4];
    const float* W2    = (const float*)d_in[5];
    const float* b2    = (const float*)d_in[6];
    const float* Wg    = (const float*)d_in[7];
    const float* bg    = (const float*)d_in[8];
    const float* bng   = (const float*)d_in[9];
    const float* bnb   = (const float*)d_in[10];
    const float* bnm   = (const float*)d_in[11];
    const float* bnv   = (const float*)d_in[12];
    const float* Wl    = (const float*)d_in[13];
    const float* bl    = (const float*)d_in[14];
    float* out = (float*)d_out;

    int N = in_sizes[0] / 64;        // requires N < 131072 (17-bit src pack)
    int E = in_sizes[1] / 2;
    int G = out_size / 2;
    int NP = ((N + 63) / 64) * 64;
    int NBUCK = (N + 127) / 128;     // <= NBUCKP
    int EB = (E + PBLK - 1) / PBLK;

    char* w = (char*)d_ws;
    int* packed2 = (int*)w;                     w += (size_t)NBUCK * ACAP * 4;
    unsigned short* hxb  = (unsigned short*)w;  w += (size_t)NP * 64 * 2;   // xb, then h
    float* gate  = (float*)w;                   w += ((size_t)N * 4 + 255) / 256 * 256;
    int* bcur0   = (int*)w;                     w += NBUCKP * 4;
    unsigned short* w1t = (unsigned short*)w;   w += 4096 * 2;
    unsigned short* w2t = (unsigned short*)w;

    const int* src = eidx;
    const int* dst = eidx + E;

    hipMemsetAsync(bcur0, 0, NBUCKP * sizeof(int), stream);

    prep_partition<<<EB, 256, 0, stream>>>(x, hxb, W1, W2, w1t, w2t,
                                           src, dst, bcur0, packed2, N, E);

    // hxb holds xb here; bucket_fused reads xb rows and writes h rows to the
    // SAME buffer.  Safe: h row for node i is only written after every read
    // of xb row i?  NO — other blocks may still read xb rows this block has
    // rewritten.  Use disjoint h region instead: h = gate area?  Keep it
    // simple and correct: write h into packed2 (dead after sort phase reads,
    // but other blocks read their arenas later...).  Safest: dedicated h.
    // (h_out below points at a fresh region carved after w2t.)
    unsigned short* hbuf = w2t + 4096;   // N*64 bf16, carved after weights

    bucket_fused  <<<NBUCK, 512, 0, stream>>>(hxb, packed2, bcur0, w1t, w2t,
                                              b1, b2, Wg, bg, hbuf, gate, N);

    pool_final    <<<G, 256, 0, stream>>>(hbuf, gate, batch, bng, bnb, bnm, bnv,
                                          Wl, bl, out, N);
}